// Round 4
// baseline (161.483 us; speedup 1.0000x reference)
//
#include <hip/hip_runtime.h>

// Problem constants: B=256, T=256, H=768, S=130
#define BB 256
#define TT 256
#define HH 768
#define SS 130
#define SP 144   // S padded to 9 n-tiles of 16

typedef __attribute__((ext_vector_type(8))) __bf16 bf16x8;
typedef __attribute__((ext_vector_type(4))) float f32x4;

__device__ __forceinline__ unsigned f2bf(float f) {
    unsigned x = __builtin_bit_cast(unsigned, f);
    x = (x + 0x7FFFu + ((x >> 16) & 1u)) >> 16;
    return x & 0xFFFFu;
}

// ---- K0: W [768][130] f32 -> wsT [144][768] bf16 (transposed; pad rows zeroed) ----
__global__ __launch_bounds__(256)
void conv_w_kernel(const float* __restrict__ W, unsigned short* __restrict__ wsT)
{
    int idx = blockIdx.x * 256 + threadIdx.x;   // over 144*768/2 bf16-pairs
    if (idx >= SP * HH / 2) return;
    int s  = idx / (HH / 2);
    int kp = idx % (HH / 2);
    unsigned u = 0;
    if (s < SS) {
        u = f2bf(W[(size_t)(2 * kp) * SS + s]) |
            (f2bf(W[(size_t)(2 * kp + 1) * SS + s]) << 16);
    }
    *(unsigned*)(wsT + (size_t)s * HH + 2 * kp) = u;
}

// ---- K1: barrier-free direct-to-register GEMM ----
// logits[b][s][t] = hidden[b][1+t][:] . W[:][s] + bias[s]
// Per wave: 16 tokens x 144 s. A frag (row=lane&15, k=(lane>>4)*8) loaded straight
// from global as 2x float4; B frag straight from wsT as one 16B load (L1-shared
// across all waves). No LDS, no __syncthreads in this kernel.
__global__ __launch_bounds__(256, 4)
void gemm_kernel(const float* __restrict__ hidden,
                 const unsigned short* __restrict__ wsT,
                 const float* __restrict__ bias,
                 float* __restrict__ logits)
{
    const int tid  = threadIdx.x;
    const int wv   = tid >> 6;
    const int lane = tid & 63;
    const int b    = blockIdx.x >> 2;
    const int tb   = (blockIdx.x & 3) << 6;          // 64-token span per block

    const int trow = tb + wv * 16 + (lane & 15);     // token this lane loads for A
    const int kq   = (lane >> 4) * 8;                // lane's k-offset within a 32-step

    const float* Abase = hidden + (size_t)b * (TT + 1) * HH + (size_t)(1 + trow) * HH + kq;
    const unsigned short* Bbase = wsT + (size_t)(lane & 15) * HH + kq;

    f32x4 acc[9];
    #pragma unroll
    for (int j = 0; j < 9; ++j) acc[j] = (f32x4){0.f, 0.f, 0.f, 0.f};

    // prologue A prefetch (k0 = 0)
    float4 pa0 = *(const float4*)(Abase);
    float4 pa1 = *(const float4*)(Abase + 4);

    for (int k0 = 0; k0 < HH; k0 += 32) {
        union { bf16x8 v; unsigned u[4]; } afu;
        afu.u[0] = f2bf(pa0.x) | (f2bf(pa0.y) << 16);
        afu.u[1] = f2bf(pa0.z) | (f2bf(pa0.w) << 16);
        afu.u[2] = f2bf(pa1.x) | (f2bf(pa1.y) << 16);
        afu.u[3] = f2bf(pa1.z) | (f2bf(pa1.w) << 16);
        bf16x8 af = afu.v;

        if (k0 + 32 < HH) {   // prefetch next step's A (hides HBM under MFMA phase)
            pa0 = *(const float4*)(Abase + k0 + 32);
            pa1 = *(const float4*)(Abase + k0 + 36);
        }

        #pragma unroll
        for (int nt = 0; nt < 9; ++nt) {
            bf16x8 bfr = *(const bf16x8*)(Bbase + (size_t)nt * 16 * HH + k0);
            acc[nt] = __builtin_amdgcn_mfma_f32_16x16x32_bf16(af, bfr, acc[nt], 0, 0, 0);
        }
    }

    // epilogue: +bias, store [b][s][t] with t-contiguous float4 per lane
    const int tq = tb + wv * 16 + (lane >> 4) * 4;   // D row = (lane>>4)*4 + r
    #pragma unroll
    for (int nt = 0; nt < 9; ++nt) {
        int s = nt * 16 + (lane & 15);                // D col = lane&15
        if (s < SS) {
            float bs = bias[s];
            float4 v = make_float4(acc[nt][0] + bs, acc[nt][1] + bs,
                                   acc[nt][2] + bs, acc[nt][3] + bs);
            *(float4*)(logits + ((size_t)b * SS + s) * TT + tq) = v;
        }
    }
}

// ---- K2: ragged segment-mean along t; one block per (s, b); high occupancy ----
__global__ __launch_bounds__(256)
void merge_kernel(const int* __restrict__ seg,
                  const float* __restrict__ logits,
                  float* __restrict__ out)
{
    __shared__ int   segl[TT];
    __shared__ int   startw[TT];
    __shared__ int   cntw[TT];
    __shared__ float row[TT];

    const int s   = blockIdx.x;
    const int b   = blockIdx.y;
    const int tid = threadIdx.x;

    segl[tid] = seg[b * TT + tid];
    cntw[tid] = 0;
    row[tid]  = logits[((size_t)b * SS + s) * TT + tid];
    __syncthreads();

    int id = segl[tid];
    if (tid == 0 || segl[tid - 1] != id) {    // run starts (seg row-sorted)
        int e = tid;
        while (e + 1 < TT && segl[e + 1] == id) ++e;
        startw[id] = tid;
        cntw[id]   = e - tid + 1;
    }
    __syncthreads();

    const int cn = cntw[tid];
    const int st = (cn > 0) ? startw[tid] : 0;
    float a = 0.f;
    for (int k = 0; k < cn; ++k) a += row[st + k];
    out[((size_t)b * SS + s) * TT + tid] = (cn > 0) ? a / (float)cn : 0.f;
}

extern "C" void kernel_launch(void* const* d_in, const int* in_sizes, int n_in,
                              void* d_out, int out_size, void* d_ws, size_t ws_size,
                              hipStream_t stream)
{
    const float* hidden = (const float*)d_in[0];  // [256, 257, 768] f32
    const float* W      = (const float*)d_in[1];  // [768, 130] f32
    const float* bias   = (const float*)d_in[2];  // [130] f32
    const int*   seg    = (const int*)d_in[3];    // [256, 256] i32 (row-sorted)
    float* out = (float*)d_out;                   // [256, 130, 256] f32

    unsigned short* wsT = (unsigned short*)d_ws;              // 221184 B
    float* logits = (float*)((char*)d_ws + 221184);           // [256][130][256] f32 = 34 MB

    (void)in_sizes; (void)n_in; (void)ws_size; (void)out_size;

    conv_w_kernel<<<dim3(SP * HH / 2 / 256), dim3(256), 0, stream>>>(W, wsT);
    gemm_kernel<<<dim3(BB * 4), dim3(256), 0, stream>>>(hidden, wsT, bias, logits);
    merge_kernel<<<dim3(SS, BB), dim3(256), 0, stream>>>(seg, logits, out);
}